// Round 6
// baseline (764.843 us; speedup 1.0000x reference)
//
#include <hip/hip_runtime.h>
#include <hip/hip_fp16.h>

#define N_ROWS 32768
#define KCODES 8192
#define CDIM   256
#define NSUB   (KCODES / 16)     // 512 subtiles of 16 codes
#define MARGIN 6.0e-4f
#define LSTR   64                // LDS row stride in bf16 units (no pad; XOR swizzle instead)

typedef __attribute__((ext_vector_type(8))) short bf16x8;
typedef __attribute__((ext_vector_type(4))) float f32x4;
typedef __attribute__((ext_vector_type(2))) _Float16 h2_t;

__device__ __forceinline__ ushort f2bf_rne(float f) {
    unsigned u = __float_as_uint(f);
    u += 0x7fffu + ((u >> 16) & 1u);
    return (ushort)(u >> 16);
}

// one DPP min step on a packed half2 (row_shr pattern; result accumulates toward lane 15)
template <int CTRL>
__device__ __forceinline__ uint dpp_min_step(uint u) {
    uint s = (uint)__builtin_amdgcn_update_dpp((int)u, (int)u, CTRL, 0xf, 0xf, false);
    h2_t a = __builtin_bit_cast(h2_t, u);
    h2_t b = __builtin_bit_cast(h2_t, s);
    return __builtin_bit_cast(uint, __builtin_elementwise_min(a, b));
}

__device__ __forceinline__ uint row16_min(uint u) {
    u = dpp_min_step<0x111>(u);   // row_shr:1
    u = dpp_min_step<0x112>(u);   // row_shr:2
    u = dpp_min_step<0x114>(u);   // row_shr:4
    u = dpp_min_step<0x118>(u);   // row_shr:8  -> lane 15 of each 16-group holds min
    return u;
}

// ---------- phase 0: fused fp32->bf16 convert + row sum-of-squares for BOTH inputs ----------
__global__ void prep_kernel(const float* __restrict__ x, const float* __restrict__ wgt,
                            ushort* __restrict__ xb, ushort* __restrict__ wb,
                            float* __restrict__ t1, float* __restrict__ e2) {
    int wave = (blockIdx.x * blockDim.x + threadIdx.x) >> 6;
    int lane = threadIdx.x & 63;
    const float* src; ushort* bdst; float* sqdst; int row;
    if (wave < N_ROWS) { src = x; bdst = xb; sqdst = t1; row = wave; }
    else               { src = wgt; bdst = wb; sqdst = e2; row = wave - N_ROWS; }
    float4 v = *((const float4*)src + (size_t)row * (CDIM / 4) + lane);
    ushort4 o;
    o.x = f2bf_rne(v.x); o.y = f2bf_rne(v.y); o.z = f2bf_rne(v.z); o.w = f2bf_rne(v.w);
    *((ushort4*)bdst + (size_t)row * (CDIM / 4) + lane) = o;
    float s = v.x * v.x + v.y * v.y + v.z * v.z + v.w * v.w;
    for (int off = 32; off; off >>= 1) s += __shfl_down(s, off, 64);
    if (lane == 0) sqdst[row] = s;
}

// ---------- phase 1: LDS-staged bf16 MFMA, XOR-swizzled LDS, DPP min epilogue ----------
// block tile: 256 rows x 128 codes; 4 waves in 2x2; wave tile: 128 rows x 64 codes
// LDS layout: row-major, 64 bf16/row, 16B chunk c stored at position (c ^ (row&7))
//  -> staging writes AND fragment reads are bank-conflict-free (8-lane permutation phases)
__launch_bounds__(256, 2)
__global__ void vq_mfma_kernel(const ushort* __restrict__ xb, const ushort* __restrict__ wb,
                               const float* __restrict__ e2, __half* __restrict__ minT) {
    __shared__ ushort xs[256 * LSTR];   // 32 KB
    __shared__ ushort ws_l[128 * LSTR]; // 16 KB
    __shared__ ushort mbT[8][264];      // transposed minima (half bits), padded stride

    const int t = threadIdx.x;
    const int w = t >> 6, lane = t & 63;
    const int ln15 = lane & 15, quad = lane >> 4;
    const int rt = blockIdx.x >> 6;     // 128 row tiles (64 consecutive blocks share X tile)
    const int ct = blockIdx.x & 63;     // 64 code tiles
    const int rbase = (w >> 1) * 128;   // wave row base (0 or 128)
    const int cbase = (w & 1) * 64;     // wave code base (0 or 64)

    // staging geometry: thread t covers rows (t>>3)+j*32, 16B chunk (t&7)
    const int srow = t >> 3, schunk = t & 7;
    const int sswz = (schunk ^ (srow & 7)) * 8;       // swizzled bf16 offset within row
    const ushort* xsrc = xb + (size_t)(rt * 256 + srow) * CDIM + schunk * 8;
    const ushort* wsrc = wb + (size_t)(ct * 128 + srow) * CDIM + schunk * 8;
    ushort* xdst = &xs[srow * LSTR + sswz];
    ushort* wdst = &ws_l[srow * LSTR + sswz];

    f32x4 acc[8][4];
#pragma unroll
    for (int mi = 0; mi < 8; ++mi)
#pragma unroll
        for (int ni = 0; ni < 4; ++ni)
#pragma unroll
            for (int r = 0; r < 4; ++r) acc[mi][ni][r] = 0.f;

    for (int cc = 0; cc < 4; ++cc) {                  // K chunks of 64
        uint4 xr[8], wr[4];
#pragma unroll
        for (int j = 0; j < 8; ++j) xr[j] = *(const uint4*)(xsrc + (size_t)j * 32 * CDIM + cc * 64);
#pragma unroll
        for (int j = 0; j < 4; ++j) wr[j] = *(const uint4*)(wsrc + (size_t)j * 32 * CDIM + cc * 64);
        __syncthreads();                              // prior readers done
#pragma unroll
        for (int j = 0; j < 8; ++j) *(uint4*)(xdst + j * 32 * LSTR) = xr[j];
#pragma unroll
        for (int j = 0; j < 4; ++j) *(uint4*)(wdst + j * 32 * LSTR) = wr[j];
        __syncthreads();
#pragma unroll
        for (int kk = 0; kk < 2; ++kk) {              // two k=32 MFMA steps per chunk
            const int swzA = (((kk * 4 + quad) ^ (ln15 & 7)) * 8);
            bf16x8 a[8], b[4];
#pragma unroll
            for (int mi = 0; mi < 8; ++mi)
                a[mi] = *(const bf16x8*)&xs[(rbase + mi * 16 + ln15) * LSTR + swzA];
#pragma unroll
            for (int ni = 0; ni < 4; ++ni)
                b[ni] = *(const bf16x8*)&ws_l[(cbase + ni * 16 + ln15) * LSTR + swzA];
#pragma unroll
            for (int mi = 0; mi < 8; ++mi)
#pragma unroll
                for (int ni = 0; ni < 4; ++ni)
                    acc[mi][ni] = __builtin_amdgcn_mfma_f32_16x16x32_bf16(a[mi], b[ni], acc[mi][ni], 0, 0, 0);
        }
    }

    // epilogue: r~ = e2 - 2s; packed-half DPP min across the 16 codes of each subtile
    float e2v[4];
#pragma unroll
    for (int ni = 0; ni < 4; ++ni) e2v[ni] = e2[ct * 128 + cbase + ni * 16 + ln15];

#pragma unroll
    for (int mi = 0; mi < 8; ++mi)
#pragma unroll
        for (int ni = 0; ni < 4; ++ni) {
            float r0 = e2v[ni] - 2.0f * acc[mi][ni][0];
            float r1 = e2v[ni] - 2.0f * acc[mi][ni][1];
            float r2 = e2v[ni] - 2.0f * acc[mi][ni][2];
            float r3 = e2v[ni] - 2.0f * acc[mi][ni][3];
            uint u01 = __builtin_bit_cast(uint, __builtin_amdgcn_cvt_pkrtz(r0, r1));
            uint u23 = __builtin_bit_cast(uint, __builtin_amdgcn_cvt_pkrtz(r2, r3));
            u01 = row16_min(u01);
            u23 = row16_min(u23);
            if (ln15 == 15) {
                int rowb = rbase + mi * 16 + quad * 4;     // rows rowb..rowb+3 (C/D layout)
                int sb   = (cbase >> 4) + ni;
                *(uint*)&mbT[sb][rowb]     = u01;          // rows rowb, rowb+1
                *(uint*)&mbT[sb][rowb + 2] = u23;          // rows rowb+2, rowb+3
            }
        }
    __syncthreads();
    {
        union { ushort s[8]; uint4 u; } r;
#pragma unroll
        for (int s = 0; s < 8; ++s) r.s[s] = mbT[s][t];
        *(uint4*)(minT + (size_t)(rt * 256 + t) * NSUB + ct * 8) = r.u;
    }
}

// ---------- phase 2: exact fp32 re-rank of candidate subtiles + fused gather ----------
__launch_bounds__(256, 2)
__global__ void vq_rerank_kernel(const float* __restrict__ x, const float* __restrict__ wgt,
                                 const float* __restrict__ t1, const float* __restrict__ e2,
                                 const __half* __restrict__ minT,
                                 float* __restrict__ out_q, float* __restrict__ out_i) {
    __shared__ float xrow[4][256];
    __shared__ int slist[4][40];
    const int t = threadIdx.x, w = t >> 6, lane = t & 63, quad = lane >> 4;
    const int row = blockIdx.x * 4 + w;

    // stage x row (1 KB) into LDS
    *(float4*)&xrow[w][lane * 4] = *((const float4*)(x + (size_t)row * CDIM) + lane);

    // read 512 subtile minima (8 per lane), wave-reduce the global approx min
    union { uint4 u; __half2 h2[4]; } raw;
    raw.u = *((const uint4*)(minT + (size_t)row * NSUB) + lane);
    float m[8];
#pragma unroll
    for (int i = 0; i < 4; ++i) {
        float2 f = __half22float2(raw.h2[i]);
        m[2 * i] = f.x;
        m[2 * i + 1] = f.y;
    }
    float lmin = m[0];
#pragma unroll
    for (int i = 1; i < 8; ++i) lmin = fminf(lmin, m[i]);
#pragma unroll
    for (int off = 1; off < 64; off <<= 1) lmin = fminf(lmin, __shfl_xor(lmin, off, 64));
    const float thresh = lmin + MARGIN;

    // build candidate subtile list (certified superset of exact-min-bin codes)
    int base = 0;
#pragma unroll
    for (int s = 0; s < 8; ++s) {
        bool c = (m[s] <= thresh);
        unsigned long long mask = __ballot(c);
        if (c) {
            int pos = base + __popcll(mask & ((1ull << lane) - 1ull));
            if (pos < 40) slist[w][pos] = lane * 8 + s;
        }
        base += (int)__popcll(mask);
    }
    const int ncand = base < 40 ? base : 40;
    __syncthreads();

    const float t1r = t1[row];
    float best = 3.402823466e38f;
    int bestk = 0x7fffffff;
    for (int p = 0; p * 4 < ncand; ++p) {
        int li = p * 4 + quad;                 // 4 subtiles per pass, 16 lanes each
        float d = 3.402823466e38f;
        int k = 0x7fffffff;
        if (li < ncand) {
            int st = slist[w][li];
            k = st * 16 + (lane & 15);
            // EXACT round-1 accumulation order: sequential c = 0..255, fmaf chain.
            // FULL unroll -> compiler hoists many independent wgt loads (latency hiding);
            // the fmaf chain itself stays serial and bit-identical.
            float acc = 0.f;
            const float4* wp = (const float4*)(wgt + (size_t)k * CDIM);
#pragma unroll
            for (int c4 = 0; c4 < 64; ++c4) {
                float4 wv = wp[c4];
                float4 xv = *(const float4*)&xrow[w][c4 * 4];
                acc = fmaf(xv.x, wv.x, acc);
                acc = fmaf(xv.y, wv.y, acc);
                acc = fmaf(xv.z, wv.z, acc);
                acc = fmaf(xv.w, wv.w, acc);
            }
            d = (t1r + e2[k]) - 2.0f * acc;    // same quantization chain as np / round 1
        }
        if (d < best || (d == best && k < bestk)) { best = d; bestk = k; }
    }
    // wave-reduce (d, k) with first-index tie-break (np argmin semantics)
#pragma unroll
    for (int off = 1; off < 64; off <<= 1) {
        float od = __shfl_xor(best, off, 64);
        int ok = __shfl_xor(bestk, off, 64);
        if (od < best || (od == best && ok < bestk)) { best = od; bestk = ok; }
    }

    // fused gather + index write
    const float4* src = (const float4*)(wgt + (size_t)bestk * CDIM);
    ((float4*)(out_q + (size_t)row * CDIM))[lane] = src[lane];
    if (lane == 0) out_i[row] = (float)bestk;
}

extern "C" void kernel_launch(void* const* d_in, const int* in_sizes, int n_in,
                              void* d_out, int out_size, void* d_ws, size_t ws_size,
                              hipStream_t stream) {
    const float* x = (const float*)d_in[0];   // (8,4096,256) fp32
    const float* wgt = (const float*)d_in[1]; // (8192,256) fp32

    float* out_q = (float*)d_out;
    float* out_i = out_q + (size_t)N_ROWS * CDIM;

    // workspace carve (all 16B aligned): e2, t1, minT, xb, wb  -> ~52.3 MB
    char* p = (char*)d_ws;
    float* e2 = (float*)p;               p += (size_t)KCODES * 4;
    float* t1 = (float*)p;               p += (size_t)N_ROWS * 4;
    __half* minT = (__half*)p;           p += (size_t)N_ROWS * NSUB * 2;
    ushort* xb = (ushort*)p;             p += (size_t)N_ROWS * CDIM * 2;
    ushort* wb = (ushort*)p;             p += (size_t)KCODES * CDIM * 2;

    prep_kernel<<<(N_ROWS + KCODES) / 4, 256, 0, stream>>>(x, wgt, xb, wb, t1, e2);

    vq_mfma_kernel<<<(N_ROWS / 256) * (KCODES / 128), 256, 0, stream>>>(xb, wb, e2, minT);
    vq_rerank_kernel<<<N_ROWS / 4, 256, 0, stream>>>(x, wgt, t1, e2, minT, out_q, out_i);
}

// Round 7
// 424.240 us; speedup vs baseline: 1.8029x; 1.8029x over previous
//
#include <hip/hip_runtime.h>
#include <hip/hip_fp16.h>

#define N_ROWS 32768
#define KCODES 8192
#define CDIM   256
#define NSUB   (KCODES / 16)     // 512 subtiles of 16 codes
#define MARGIN 4.0e-4f           // certified need ~2e-4 (bf16 score + bin + fp16 storage); 2x slack
#define LSTR   64                // LDS row stride in bf16 units (no pad; XOR swizzle instead)

typedef __attribute__((ext_vector_type(8))) short bf16x8;
typedef __attribute__((ext_vector_type(4))) float f32x4;
typedef __attribute__((ext_vector_type(2))) _Float16 h2_t;

__device__ __forceinline__ ushort f2bf_rne(float f) {
    unsigned u = __float_as_uint(f);
    u += 0x7fffu + ((u >> 16) & 1u);
    return (ushort)(u >> 16);
}

// one DPP min step on a packed half2 (row_shr pattern; result accumulates toward lane 15)
template <int CTRL>
__device__ __forceinline__ uint dpp_min_step(uint u) {
    uint s = (uint)__builtin_amdgcn_update_dpp((int)u, (int)u, CTRL, 0xf, 0xf, false);
    h2_t a = __builtin_bit_cast(h2_t, u);
    h2_t b = __builtin_bit_cast(h2_t, s);
    return __builtin_bit_cast(uint, __builtin_elementwise_min(a, b));
}

__device__ __forceinline__ uint row16_min(uint u) {
    u = dpp_min_step<0x111>(u);   // row_shr:1
    u = dpp_min_step<0x112>(u);   // row_shr:2
    u = dpp_min_step<0x114>(u);   // row_shr:4
    u = dpp_min_step<0x118>(u);   // row_shr:8  -> lane 15 of each 16-group holds min
    return u;
}

// ---------- phase 0: fused fp32->bf16 convert + row sum-of-squares for BOTH inputs ----------
__global__ void prep_kernel(const float* __restrict__ x, const float* __restrict__ wgt,
                            ushort* __restrict__ xb, ushort* __restrict__ wb,
                            float* __restrict__ t1, float* __restrict__ e2) {
    int wave = (blockIdx.x * blockDim.x + threadIdx.x) >> 6;
    int lane = threadIdx.x & 63;
    const float* src; ushort* bdst; float* sqdst; int row;
    if (wave < N_ROWS) { src = x; bdst = xb; sqdst = t1; row = wave; }
    else               { src = wgt; bdst = wb; sqdst = e2; row = wave - N_ROWS; }
    float4 v = *((const float4*)src + (size_t)row * (CDIM / 4) + lane);
    ushort4 o;
    o.x = f2bf_rne(v.x); o.y = f2bf_rne(v.y); o.z = f2bf_rne(v.z); o.w = f2bf_rne(v.w);
    *((ushort4*)bdst + (size_t)row * (CDIM / 4) + lane) = o;
    float s = v.x * v.x + v.y * v.y + v.z * v.z + v.w * v.w;
    for (int off = 32; off; off >>= 1) s += __shfl_down(s, off, 64);
    if (lane == 0) sqdst[row] = s;
}

// ---------- phase 1: LDS-staged bf16 MFMA, XOR-swizzled LDS, DPP min epilogue ----------
// block tile: 256 rows x 128 codes; 4 waves in 2x2; wave tile: 128 rows x 64 codes
// LDS layout: row-major, 64 bf16/row, 16B chunk c stored at position (c ^ (row&7))
//  -> staging writes AND fragment reads are bank-conflict-free (8-lane permutation phases)
// Staging is load->store interleaved (<=1 live uint4) to avoid the round-5/6 register-hold spill.
__launch_bounds__(256, 2)
__global__ void vq_mfma_kernel(const ushort* __restrict__ xb, const ushort* __restrict__ wb,
                               const float* __restrict__ e2, __half* __restrict__ minT) {
    __shared__ ushort xs[256 * LSTR];   // 32 KB
    __shared__ ushort ws_l[128 * LSTR]; // 16 KB
    __shared__ ushort mbT[8][264];      // transposed minima (half bits), padded stride

    const int t = threadIdx.x;
    const int w = t >> 6, lane = t & 63;
    const int ln15 = lane & 15, quad = lane >> 4;
    const int rt = blockIdx.x >> 6;     // 128 row tiles (64 consecutive blocks share X tile)
    const int ct = blockIdx.x & 63;     // 64 code tiles
    const int rbase = (w >> 1) * 128;   // wave row base (0 or 128)
    const int cbase = (w & 1) * 64;     // wave code base (0 or 64)

    // staging geometry: thread t covers rows (t>>3)+j*32, 16B chunk (t&7)
    const int srow = t >> 3, schunk = t & 7;
    const int sswz = (schunk ^ (srow & 7)) * 8;       // swizzled bf16 offset within row
    const ushort* xsrc = xb + (size_t)(rt * 256 + srow) * CDIM + schunk * 8;
    const ushort* wsrc = wb + (size_t)(ct * 128 + srow) * CDIM + schunk * 8;
    ushort* xdst = &xs[srow * LSTR + sswz];
    ushort* wdst = &ws_l[srow * LSTR + sswz];

    f32x4 acc[8][4];
#pragma unroll
    for (int mi = 0; mi < 8; ++mi)
#pragma unroll
        for (int ni = 0; ni < 4; ++ni)
#pragma unroll
            for (int r = 0; r < 4; ++r) acc[mi][ni][r] = 0.f;

    for (int cc = 0; cc < 4; ++cc) {                  // K chunks of 64
        __syncthreads();                              // prior readers done
        // stage X: 256 rows x 64 cols; load->store immediately (no long register holds)
#pragma unroll
        for (int j = 0; j < 8; ++j) {
            uint4 v = *(const uint4*)(xsrc + (size_t)j * 32 * CDIM + cc * 64);
            *(uint4*)(xdst + j * 32 * LSTR) = v;
        }
        // stage W: 128 rows x 64 cols
#pragma unroll
        for (int j = 0; j < 4; ++j) {
            uint4 v = *(const uint4*)(wsrc + (size_t)j * 32 * CDIM + cc * 64);
            *(uint4*)(wdst + j * 32 * LSTR) = v;
        }
        __syncthreads();
#pragma unroll
        for (int kk = 0; kk < 2; ++kk) {              // two k=32 MFMA steps per chunk
            const int swzA = (((kk * 4 + quad) ^ (ln15 & 7)) * 8);
            bf16x8 a[8], b[4];
#pragma unroll
            for (int mi = 0; mi < 8; ++mi)
                a[mi] = *(const bf16x8*)&xs[(rbase + mi * 16 + ln15) * LSTR + swzA];
#pragma unroll
            for (int ni = 0; ni < 4; ++ni)
                b[ni] = *(const bf16x8*)&ws_l[(cbase + ni * 16 + ln15) * LSTR + swzA];
#pragma unroll
            for (int mi = 0; mi < 8; ++mi)
#pragma unroll
                for (int ni = 0; ni < 4; ++ni)
                    acc[mi][ni] = __builtin_amdgcn_mfma_f32_16x16x32_bf16(a[mi], b[ni], acc[mi][ni], 0, 0, 0);
        }
    }

    // epilogue: r~ = e2 - 2s; packed-half DPP min across the 16 codes of each subtile
    float e2v[4];
#pragma unroll
    for (int ni = 0; ni < 4; ++ni) e2v[ni] = e2[ct * 128 + cbase + ni * 16 + ln15];

#pragma unroll
    for (int mi = 0; mi < 8; ++mi)
#pragma unroll
        for (int ni = 0; ni < 4; ++ni) {
            float r0 = e2v[ni] - 2.0f * acc[mi][ni][0];
            float r1 = e2v[ni] - 2.0f * acc[mi][ni][1];
            float r2 = e2v[ni] - 2.0f * acc[mi][ni][2];
            float r3 = e2v[ni] - 2.0f * acc[mi][ni][3];
            uint u01 = __builtin_bit_cast(uint, __builtin_amdgcn_cvt_pkrtz(r0, r1));
            uint u23 = __builtin_bit_cast(uint, __builtin_amdgcn_cvt_pkrtz(r2, r3));
            u01 = row16_min(u01);
            u23 = row16_min(u23);
            if (ln15 == 15) {
                int rowb = rbase + mi * 16 + quad * 4;     // rows rowb..rowb+3 (C/D layout)
                int sb   = (cbase >> 4) + ni;
                *(uint*)&mbT[sb][rowb]     = u01;          // rows rowb, rowb+1
                *(uint*)&mbT[sb][rowb + 2] = u23;          // rows rowb+2, rowb+3
            }
        }
    __syncthreads();
    {
        union { ushort s[8]; uint4 u; } r;
#pragma unroll
        for (int s = 0; s < 8; ++s) r.s[s] = mbT[s][t];
        *(uint4*)(minT + (size_t)(rt * 256 + t) * NSUB + ct * 8) = r.u;
    }
}

// ---------- phase 2: exact fp32 re-rank of candidate subtiles + fused gather ----------
__launch_bounds__(256, 4)
__global__ void vq_rerank_kernel(const float* __restrict__ x, const float* __restrict__ wgt,
                                 const float* __restrict__ t1, const float* __restrict__ e2,
                                 const __half* __restrict__ minT,
                                 float* __restrict__ out_q, float* __restrict__ out_i) {
    __shared__ float xrow[4][256];
    __shared__ int slist[4][40];
    const int t = threadIdx.x, w = t >> 6, lane = t & 63, quad = lane >> 4;
    const int row = blockIdx.x * 4 + w;

    // stage x row (1 KB) into LDS
    *(float4*)&xrow[w][lane * 4] = *((const float4*)(x + (size_t)row * CDIM) + lane);

    // read 512 subtile minima (8 per lane), wave-reduce the global approx min
    union { uint4 u; __half2 h2[4]; } raw;
    raw.u = *((const uint4*)(minT + (size_t)row * NSUB) + lane);
    float m[8];
#pragma unroll
    for (int i = 0; i < 4; ++i) {
        float2 f = __half22float2(raw.h2[i]);
        m[2 * i] = f.x;
        m[2 * i + 1] = f.y;
    }
    float lmin = m[0];
#pragma unroll
    for (int i = 1; i < 8; ++i) lmin = fminf(lmin, m[i]);
#pragma unroll
    for (int off = 1; off < 64; off <<= 1) lmin = fminf(lmin, __shfl_xor(lmin, off, 64));
    const float thresh = lmin + MARGIN;

    // build candidate subtile list (certified superset of exact-min-bin codes)
    int base = 0;
#pragma unroll
    for (int s = 0; s < 8; ++s) {
        bool c = (m[s] <= thresh);
        unsigned long long mask = __ballot(c);
        if (c) {
            int pos = base + __popcll(mask & ((1ull << lane) - 1ull));
            if (pos < 40) slist[w][pos] = lane * 8 + s;
        }
        base += (int)__popcll(mask);
    }
    const int ncand = base < 40 ? base : 40;
    __syncthreads();

    const float t1r = t1[row];
    float best = 3.402823466e38f;
    int bestk = 0x7fffffff;
    for (int p = 0; p * 4 < ncand; ++p) {
        int li = p * 4 + quad;                 // 4 subtiles per pass, 16 lanes each
        float d = 3.402823466e38f;
        int k = 0x7fffffff;
        if (li < ncand) {
            int st = slist[w][li];
            k = st * 16 + (lane & 15);
            // EXACT round-1 accumulation order: sequential c = 0..255, fmaf chain.
            // FULL unroll -> compiler batches independent wgt loads ahead of the chain.
            float acc = 0.f;
            const float4* wp = (const float4*)(wgt + (size_t)k * CDIM);
#pragma unroll
            for (int c4 = 0; c4 < 64; ++c4) {
                float4 wv = wp[c4];
                float4 xv = *(const float4*)&xrow[w][c4 * 4];
                acc = fmaf(xv.x, wv.x, acc);
                acc = fmaf(xv.y, wv.y, acc);
                acc = fmaf(xv.z, wv.z, acc);
                acc = fmaf(xv.w, wv.w, acc);
            }
            d = (t1r + e2[k]) - 2.0f * acc;    // same quantization chain as np / round 1
        }
        if (d < best || (d == best && k < bestk)) { best = d; bestk = k; }
    }
    // wave-reduce (d, k) with first-index tie-break (np argmin semantics)
#pragma unroll
    for (int off = 1; off < 64; off <<= 1) {
        float od = __shfl_xor(best, off, 64);
        int ok = __shfl_xor(bestk, off, 64);
        if (od < best || (od == best && ok < bestk)) { best = od; bestk = ok; }
    }

    // fused gather + index write
    const float4* src = (const float4*)(wgt + (size_t)bestk * CDIM);
    ((float4*)(out_q + (size_t)row * CDIM))[lane] = src[lane];
    if (lane == 0) out_i[row] = (float)bestk;
}

extern "C" void kernel_launch(void* const* d_in, const int* in_sizes, int n_in,
                              void* d_out, int out_size, void* d_ws, size_t ws_size,
                              hipStream_t stream) {
    const float* x = (const float*)d_in[0];   // (8,4096,256) fp32
    const float* wgt = (const float*)d_in[1]; // (8192,256) fp32

    float* out_q = (float*)d_out;
    float* out_i = out_q + (size_t)N_ROWS * CDIM;

    // workspace carve (all 16B aligned): e2, t1, minT, xb, wb  -> ~52.3 MB
    char* p = (char*)d_ws;
    float* e2 = (float*)p;               p += (size_t)KCODES * 4;
    float* t1 = (float*)p;               p += (size_t)N_ROWS * 4;
    __half* minT = (__half*)p;           p += (size_t)N_ROWS * NSUB * 2;
    ushort* xb = (ushort*)p;             p += (size_t)N_ROWS * CDIM * 2;
    ushort* wb = (ushort*)p;             p += (size_t)KCODES * CDIM * 2;

    prep_kernel<<<(N_ROWS + KCODES) / 4, 256, 0, stream>>>(x, wgt, xb, wb, t1, e2);

    vq_mfma_kernel<<<(N_ROWS / 256) * (KCODES / 128), 256, 0, stream>>>(xb, wb, e2, minT);
    vq_rerank_kernel<<<N_ROWS / 4, 256, 0, stream>>>(x, wgt, t1, e2, minT, out_q, out_i);
}